// Round 3
// baseline (1369.539 us; speedup 1.0000x reference)
//
#include <hip/hip_runtime.h>

#define T_TOK 65536
#define HDIM  1024
#define NSEG  64
#define BM 128
#define BN 128
#define BK 64

typedef _Float16 half8  __attribute__((ext_vector_type(8)));
typedef float    f32x4  __attribute__((ext_vector_type(4)));
typedef float    f32x16 __attribute__((ext_vector_type(16)));

// ---- workspace layout (bytes) ----
#define WP_OFF   0ull                     // _Float16[1024*1024]: W packed fragment-major
#define U0_OFF   2097152ull               // float[1024]: gamma*Wout[:,0]
#define U1_OFF   (U0_OFF + 4096ull)       // float[1024]: gamma*Wout[:,1]
#define CON_OFF  (U1_OFF + 4096ull)       // float[4]: G0,G1,Bt0,Bt1
#define ACC_OFF  (CON_OFF + 64ull)        // float[64*2] segment logit sums
#define CNT_OFF  (ACC_OFF + 512ull)       // int[64] segment counts
#define RF_OFF   (CNT_OFF + 256ull)       // float[T_TOK*4] per-row S1,S2,P0,P1

__device__ __forceinline__ void gload_lds16(const void* g, void* l) {
    __builtin_amdgcn_global_load_lds(
        (const __attribute__((address_space(1))) unsigned int*)g,
        (__attribute__((address_space(3))) unsigned int*)l, 16, 0, 0);
}

// ---------------------------------------------------------------------------
// k0: u-vectors, consts, segment counts (sorted ids -> boundary scan).
// ---------------------------------------------------------------------------
__global__ void prep_kernel(const float* __restrict__ gamma, const float* __restrict__ beta,
                            const float* __restrict__ wout, const int* __restrict__ segids,
                            float* __restrict__ u0, float* __restrict__ u1,
                            float* __restrict__ consts, int* __restrict__ counts) {
    __shared__ int   starts[65];
    __shared__ float cacc[4];
    int tid = threadIdx.x;                       // blockDim = 1024 = HDIM
    if (tid < 4)   cacc[tid] = 0.f;
    if (tid == 0) { starts[0] = 0; starts[64] = T_TOK; }
    __syncthreads();

    float g  = gamma[tid], be = beta[tid];
    float w0 = wout[2 * tid], w1 = wout[2 * tid + 1];
    float a0 = g * w0, a1 = g * w1;
    u0[tid] = a0; u1[tid] = a1;
    float v[4] = {a0, a1, be * w0, be * w1};
#pragma unroll
    for (int q = 0; q < 4; ++q) {
        float x = v[q];
#pragma unroll
        for (int off = 32; off > 0; off >>= 1) x += __shfl_down(x, off, 64);
        if ((tid & 63) == 0) atomicAdd(&cacc[q], x);
    }
    for (int i = tid; i < T_TOK - 1; i += 1024) {
        int s0 = segids[i], s1 = segids[i + 1];
        if (s1 != s0) starts[s1] = i + 1;
    }
    __syncthreads();
    if (tid < 64) counts[tid] = starts[tid + 1] - starts[tid];
    if (tid < 4)  consts[tid] = cacc[tid];
}

// ---------------------------------------------------------------------------
// k1: W [k][col] fp32 -> Wp fragment-major fp16.
// Wp[((ct*64 + ksg)*64 + lane)*8 + j] = W[ksg*16 + (lane>>5)*8 + j][ct*32 + (lane&31)]
// One (ct,ksg) chunk = contiguous 1 KB = exactly one global_load_lds x4 per wave.
// ---------------------------------------------------------------------------
__global__ void wpack_kernel(const float* __restrict__ W, _Float16* __restrict__ Wp) {
    __shared__ float tile[64][65];       // [kloc][cloc]
    int bx = blockIdx.x & 15;            // col tile (64 cols)
    int by = blockIdx.x >> 4;            // k tile (64 k)
    int c0 = bx * 64, k0 = by * 64;
    int t  = threadIdx.x;                // 256 threads
    int kk = t >> 6, cc = t & 63;
#pragma unroll
    for (int i = 0; i < 16; ++i) {
        int kl = kk * 16 + i;
        tile[kl][cc] = W[(size_t)(k0 + kl) * HDIM + c0 + cc];   // coalesced
    }
    __syncthreads();
    int cti  = t >> 7;                   // 0..1
    int ksgi = (t >> 5) & 3;             // 0..3
    int ln   = t & 31;
    int ct   = (c0 >> 5) + cti;
    int ksg  = (k0 >> 4) + ksgi;
#pragma unroll
    for (int lh = 0; lh < 2; ++lh) {
        int l = lh * 32 + ln;
        half8 v;
#pragma unroll
        for (int j = 0; j < 8; ++j)
            v[j] = (_Float16)tile[ksgi * 16 + lh * 8 + j][cti * 32 + ln];
        *(half8*)(Wp + ((size_t)(ct * 64 + ksg) * 64 + l) * 8) = v;  // coalesced 16B/lane
    }
}

// ---------------------------------------------------------------------------
// k2: 128x128-tile GEMM (m97 geometry) + fused bias/residual functional
// epilogue. 4096 blocks x 256 threads (4 waves, 2x2). bid: row=bid>>3, col=bid&7.
// A: fp32 HBM -> cvt fp16 -> LDS fragment chunks. B: Wp -> LDS via
// global_load_lds width 16 (zero VGPR traffic). Per-block partial LN
// functionals atomically added to rowfunc[T][4].
// ---------------------------------------------------------------------------
__global__ __launch_bounds__(256, 4) void gemm_kernel(
    const float* __restrict__ A, const float* __restrict__ R,
    const float* __restrict__ bdense, const _Float16* __restrict__ Wp,
    const float* __restrict__ u0g, const float* __restrict__ u1g,
    float* __restrict__ rowfunc) {
    __shared__ __align__(16) _Float16 lds[BM * BK + BN * BK];  // 32 KB
    _Float16* aS = lds;            // [ksgi4][rt4][lane64][8]
    _Float16* bS = lds + BM * BK;  // [cti4][ksgi4][lane64][8]

    int tid  = threadIdx.x;
    int lane = tid & 63, wave = tid >> 6;      // 4 waves
    int wr = wave >> 1, wc = wave & 1;         // 2x2 wave grid
    int ln = lane & 31, lh = lane >> 5;
    int rowBase = (blockIdx.x >> 3) * BM;
    int colg    = blockIdx.x & 7;              // 128-col group
    int ct0     = colg * 4;                    // first 32-col tile

    f32x16 acc[2][2];
#pragma unroll
    for (int tr = 0; tr < 2; ++tr)
#pragma unroll
        for (int tc = 0; tc < 2; ++tc)
#pragma unroll
            for (int i = 0; i < 16; ++i) acc[tr][tc][i] = 0.f;

    int sr = tid & 127;          // staging row 0..127
    int sh = tid >> 7;           // staging k-half (32 floats each)
    const float* aSrc = A + (size_t)(rowBase + sr) * HDIM + sh * 32;
    int aDstBase[4];             // LDS half-index per j
#pragma unroll
    for (int j = 0; j < 4; ++j) {
        int ksgi = sh * 2 + (j >> 1), lhf = j & 1;
        aDstBase[j] = ((ksgi * 4 + (sr >> 5)) * 64 + (sr & 31) + 32 * lhf) * 8;
    }

    for (int kc = 0; kc < 16; ++kc) {
        __syncthreads();   // previous chunk consumed
        // ---- B: 16 chunks of 1 KB via global_load_lds, 4 per wave ----
#pragma unroll
        for (int i = 0; i < 4; ++i) {
            int idx  = wave * 4 + i;
            int cti  = idx >> 2, ksgi = idx & 3;
            int chunk = (ct0 + cti) * 64 + kc * 4 + ksgi;
            gload_lds16(Wp + (size_t)chunk * 512 + lane * 8,
                        bS + (size_t)(cti * 4 + ksgi) * 512);
        }
        // ---- A: 128 rows x 64 k fp32 -> fp16 chunks ----
        const float* s = aSrc + kc * 64;
#pragma unroll
        for (int j = 0; j < 4; ++j) {
            f32x4 a0 = *(const f32x4*)(s + j * 8);
            f32x4 a1 = *(const f32x4*)(s + j * 8 + 4);
            half8 hh;
            hh[0] = (_Float16)a0[0]; hh[1] = (_Float16)a0[1];
            hh[2] = (_Float16)a0[2]; hh[3] = (_Float16)a0[3];
            hh[4] = (_Float16)a1[0]; hh[5] = (_Float16)a1[1];
            hh[6] = (_Float16)a1[2]; hh[7] = (_Float16)a1[3];
            *(half8*)(aS + aDstBase[j]) = hh;
        }
        __syncthreads();   // stage complete (incl. vmcnt drain of global_load_lds)
        // ---- 4 K-steps of K=16 ----
#pragma unroll
        for (int ks = 0; ks < 4; ++ks) {
            half8 afr[2], bfr[2];
#pragma unroll
            for (int tr = 0; tr < 2; ++tr)
                afr[tr] = *(const half8*)(aS + ((ks * 4 + wr * 2 + tr) * 64 + lane) * 8);
#pragma unroll
            for (int tc = 0; tc < 2; ++tc)
                bfr[tc] = *(const half8*)(bS + (((wc * 2 + tc) * 4 + ks) * 64 + lane) * 8);
#pragma unroll
            for (int tr = 0; tr < 2; ++tr)
#pragma unroll
                for (int tc = 0; tc < 2; ++tc)
                    acc[tr][tc] = __builtin_amdgcn_mfma_f32_32x32x16_f16(
                        afr[tr], bfr[tc], acc[tr][tc], 0, 0, 0);
        }
    }

    // ---- epilogue: h = acc + b + r ; per-row partial S1,S2,P0,P1 ----
    __syncthreads();
    float* red = (float*)lds;           // [4 q][128 row][16] = 32 KB
#pragma unroll
    for (int i = 0; i < 8; ++i)
        *(f32x4*)(red + (tid + i * 256) * 4) = (f32x4){0.f, 0.f, 0.f, 0.f};
    __syncthreads();

    float bv[2], u0v[2], u1v[2];
#pragma unroll
    for (int tc = 0; tc < 2; ++tc) {
        int c = colg * 128 + wc * 64 + tc * 32 + ln;
        bv[tc] = bdense[c]; u0v[tc] = u0g[c]; u1v[tc] = u1g[c];
    }
    int sl = ln & 15;
#pragma unroll
    for (int tr = 0; tr < 2; ++tr)
#pragma unroll
        for (int reg = 0; reg < 16; ++reg) {
            int row128 = wr * 64 + tr * 32 + ((reg & 3) + 8 * (reg >> 2) + 4 * lh);
            const float* rrow = R + (size_t)(rowBase + row128) * HDIM
                                  + colg * 128 + wc * 64 + ln;
            float s1 = 0.f, s2 = 0.f, p0 = 0.f, p1 = 0.f;
#pragma unroll
            for (int tc = 0; tc < 2; ++tc) {
                float h = acc[tr][tc][reg] + bv[tc] + rrow[tc * 32];
                s1 += h; s2 += h * h; p0 += h * u0v[tc]; p1 += h * u1v[tc];
            }
            atomicAdd(&red[(0 * 128 + row128) * 16 + sl], s1);
            atomicAdd(&red[(1 * 128 + row128) * 16 + sl], s2);
            atomicAdd(&red[(2 * 128 + row128) * 16 + sl], p0);
            atomicAdd(&red[(3 * 128 + row128) * 16 + sl], p1);
        }
    __syncthreads();
    // combine 16 partials per (q,row) and add to global rowfunc
#pragma unroll
    for (int s = 0; s < 2; ++s) {
        int slot = tid + s * 256;            // 512 slots
        int q = slot >> 7, row = slot & 127;
        const float* p = red + (size_t)(q * 128 + row) * 16;
        f32x4 v0 = *(const f32x4*)p,       v1 = *(const f32x4*)(p + 4);
        f32x4 v2 = *(const f32x4*)(p + 8), v3 = *(const f32x4*)(p + 12);
        float sum = (v0[0] + v0[1] + v0[2] + v0[3]) + (v1[0] + v1[1] + v1[2] + v1[3])
                  + (v2[0] + v2[1] + v2[2] + v2[3]) + (v3[0] + v3[1] + v3[2] + v3[3]);
        atomicAdd(&rowfunc[(size_t)(rowBase + row) * 4 + q], sum);
    }
}

// ---------------------------------------------------------------------------
// k3: per-row LN algebra -> logits; segment-run combine -> segacc atomics.
// ---------------------------------------------------------------------------
__global__ void logits_kernel(const float* __restrict__ rowfunc, const float* __restrict__ consts,
                              const int* __restrict__ segids, float* __restrict__ segacc) {
    __shared__ float sval[256][2];
    __shared__ int   sseg[256];
    int t   = threadIdx.x;
    int row = blockIdx.x * 256 + t;
    f32x4 f = *(const f32x4*)(rowfunc + (size_t)row * 4);
    float mu  = f[0] * (1.f / 1024.f);
    float var = f[1] * (1.f / 1024.f) - mu * mu;
    float rsd = rsqrtf(var + 1e-12f);
    sval[t][0] = rsd * (f[2] - mu * consts[0]) + consts[2];
    sval[t][1] = rsd * (f[3] - mu * consts[1]) + consts[3];
    sseg[t] = segids[row];
    __syncthreads();
    int sg = sseg[t];
    if (t == 255 || sseg[t + 1] != sg) {     // run boundary (block-local)
        float a0 = 0.f, a1 = 0.f;
        int rr = t;
        while (rr >= 0 && sseg[rr] == sg) { a0 += sval[rr][0]; a1 += sval[rr][1]; --rr; }
        atomicAdd(&segacc[sg * 2],     a0);
        atomicAdd(&segacc[sg * 2 + 1], a1);
    }
}

// ---------------------------------------------------------------------------
// k4: logits[b][l] = segacc[b][l] / count[b] + b_out[l]
// ---------------------------------------------------------------------------
__global__ void finalize_kernel(const float* __restrict__ segacc, const int* __restrict__ counts,
                                const float* __restrict__ bout, float* __restrict__ out) {
    int t = threadIdx.x;
    if (t < 128) {
        int s = t >> 1, l = t & 1;
        out[t] = segacc[t] / (float)counts[s] + bout[l];
    }
}

extern "C" void kernel_launch(void* const* d_in, const int* in_sizes, int n_in,
                              void* d_out, int out_size, void* d_ws, size_t ws_size,
                              hipStream_t stream) {
    const float* A      = (const float*)d_in[0];  // sequence_attention_embeddings [T,H]
    const float* R      = (const float*)d_in[1];  // sequence_embeddings [T,H]
    const float* Wd     = (const float*)d_in[2];  // W_dense [H,H]
    const float* bdense = (const float*)d_in[3];  // b_dense [H]
    const float* gamma  = (const float*)d_in[4];  // gamma [H]
    const float* beta   = (const float*)d_in[5];  // beta [H]
    const float* wout   = (const float*)d_in[6];  // W_out [H,2]
    const float* bout   = (const float*)d_in[7];  // b_out [2]
    const int*   segids = (const int*)d_in[8];    // segment_ids [T]
    float* out = (float*)d_out;

    char* ws = (char*)d_ws;
    _Float16* Wp   = (_Float16*)(ws + WP_OFF);
    float* u0      = (float*)(ws + U0_OFF);
    float* u1      = (float*)(ws + U1_OFF);
    float* consts  = (float*)(ws + CON_OFF);
    float* segacc  = (float*)(ws + ACC_OFF);
    int*   counts  = (int*)(ws + CNT_OFF);
    float* rowfunc = (float*)(ws + RF_OFF);

    hipMemsetAsync(segacc, 0, 512, stream);
    hipMemsetAsync(rowfunc, 0, (size_t)T_TOK * 4 * sizeof(float), stream);
    prep_kernel<<<1, 1024, 0, stream>>>(gamma, beta, wout, segids, u0, u1, consts, counts);
    wpack_kernel<<<256, 256, 0, stream>>>(Wd, Wp);
    gemm_kernel<<<4096, 256, 0, stream>>>(A, R, bdense, Wp, u0, u1, rowfunc);
    logits_kernel<<<T_TOK / 256, 256, 0, stream>>>(rowfunc, consts, segids, segacc);
    finalize_kernel<<<1, 128, 0, stream>>>(segacc, counts, bout, out);
}